// Round 9
// baseline (643.132 us; speedup 1.0000x reference)
//
#include <hip/hip_runtime.h>
#include <hip/hip_bf16.h>

#define TT    1024
#define BATCH 512
#define HH    128
#define II    64
#define BC    16
#define NTHR  512
#define CHUNK 8
#define XROW  72   // shorts per x row: 64 data + 8 pad
#define HROW  136  // shorts per h row: 128 data + 8 pad
#define L2E   1.4426950408889634f

typedef __attribute__((ext_vector_type(8))) short bhalf8;
typedef __attribute__((ext_vector_type(4))) short bhalf4;
typedef __attribute__((ext_vector_type(4))) float f32x4;

static __device__ __forceinline__ unsigned cvtpk(float lo, float hi) {
  unsigned r;
  asm("v_cvt_pk_bf16_f32 %0, %1, %2" : "=v"(r) : "v"(lo), "v"(hi));
  return r;
}
static __device__ __forceinline__ float bf2f(short s) {
  return __builtin_bit_cast(float, ((unsigned)(unsigned short)s) << 16);
}
static __device__ __forceinline__ f32x4 mfma16(bhalf8 a, bhalf8 b, f32x4 c) {
  return __builtin_amdgcn_mfma_f32_16x16x32_bf16(a, b, c, 0, 0, 0);
}
static __device__ __forceinline__ bhalf8 packrow8s(const float* p, float s) {
  union { bhalf8 v; unsigned u[4]; } cv;
  cv.u[0] = cvtpk(p[0] * s, p[1] * s);
  cv.u[1] = cvtpk(p[2] * s, p[3] * s);
  cv.u[2] = cvtpk(p[4] * s, p[5] * s);
  cv.u[3] = cvtpk(p[6] * s, p[7] * s);
  return cv.v;
}
// barrier without vmcnt drain; lgkmcnt(0) orders LDS
static __device__ __forceinline__ void bar_lgkm() {
  asm volatile("s_waitcnt lgkmcnt(0)\n\ts_barrier" ::: "memory");
}

// sigmoid LUT index: x-hat in exp2 domain (weights prescaled by log2e).
// 4096 entries over [-8, 8): i = round(xh*256 + 2048), clamped via med3.
// Quantization err <= 0.173/512 = 3.4e-4; |xh|>8 is ~11 sigma (never hit).
#define SIDX(v_) \
  __builtin_amdgcn_fmed3f(fmaf((v_), 256.0f, 2048.5f), 0.0f, 4095.0f)

// One GRU step (R5 structure = measured best; only r/z sigmoids LUT-ized).
// Shared-ALU model: step = MFMA-cycles + VALU-cycles per SIMD; LUT moves
// 2 trans-trios (36cy/elem) off the ALU into the LDS pipe (8cy index VALU).
#define DOSTEP(TP, AR, AZ, AXN, BR, BZ, BXN)                                    \
  {                                                                             \
    constexpr int tp = (TP);                                                    \
    const short* hrow = (tp & 1) ? hrd1 : hrd0;                                 \
    bhalf8 hf0 = *(const bhalf8*)(hrow + q * 8);                                \
    bhalf8 hf1 = *(const bhalf8*)(hrow + 32 + q * 8);                           \
    bhalf8 hf2 = *(const bhalf8*)(hrow + 64 + q * 8);                           \
    bhalf8 hf3 = *(const bhalf8*)(hrow + 96 + q * 8);                           \
    const int nb2 = (tp == 7) ? ((c + 1) & 1) : (c & 1);                        \
    const short* xrow = xbase + nb2 * (CHUNK * BC * XROW)                       \
                              + ((tp + 1) & 7) * (BC * XROW);                   \
    bhalf8 xf0 = *(const bhalf8*)(xrow + q * 8);                                \
    bhalf8 xf1 = *(const bhalf8*)(xrow + 32 + q * 8);                           \
    if (tp == 0 && more) { /* issue next-chunk global loads */                  \
      const float* sA = xsrcA + (size_t)(c + 1) * (CHUNK * II);                 \
      xl0 = *(const float4*)(sA);                                               \
      xl1 = *(const float4*)(sA + 4);                                           \
      xl2 = *(const float4*)(sA + 4 * II);                                      \
      xl3 = *(const float4*)(sA + 4 * II + 4);                                  \
    }                                                                           \
    /* h-side MFMAs, grouped by acc chain (ar first -> r lookups start early)*/ \
    AR  = mfma16(whh[0][0], hf0, AR);  AR  = mfma16(whh[0][1], hf1, AR);        \
    AR  = mfma16(whh[0][2], hf2, AR);  AR  = mfma16(whh[0][3], hf3, AR);        \
    AZ  = mfma16(whh[1][0], hf0, AZ);  AZ  = mfma16(whh[1][1], hf1, AZ);        \
    AZ  = mfma16(whh[1][2], hf2, AZ);  AZ  = mfma16(whh[1][3], hf3, AZ);        \
    f32x4 ahn = mfma16(whh[2][0], hf0, bias_hn);                                \
    ahn = mfma16(whh[2][1], hf1, ahn);                                          \
    ahn = mfma16(whh[2][2], hf2, ahn);                                          \
    ahn = mfma16(whh[2][3], hf3, ahn);                                          \
    /* r,z gates: LUT gathers (8 ds_read_b32 in flight over the x-MFMAs) */     \
    const float rg0 = slut[(uint)SIDX(AR[0])];                                  \
    const float rg1 = slut[(uint)SIDX(AR[1])];                                  \
    const float rg2 = slut[(uint)SIDX(AR[2])];                                  \
    const float rg3 = slut[(uint)SIDX(AR[3])];                                  \
    BR = mfma16(wih[0][0], xf0, bias_r);                                        \
    BR = mfma16(wih[0][1], xf1, BR);                                            \
    const float zg0 = slut[(uint)SIDX(AZ[0])];                                  \
    const float zg1 = slut[(uint)SIDX(AZ[1])];                                  \
    const float zg2 = slut[(uint)SIDX(AZ[2])];                                  \
    const float zg3 = slut[(uint)SIDX(AZ[3])];                                  \
    BZ = mfma16(wih[1][0], xf0, bias_z);                                        \
    BZ = mfma16(wih[1][1], xf1, BZ);                                            \
    /* n gate: exact trans trio (accuracy anchor) + h update */                 \
    {                                                                           \
      const float na0 = fmaf(rg0, ahn[0], AXN[0]);                              \
      const float na1 = fmaf(rg1, ahn[1], AXN[1]);                              \
      const float na2 = fmaf(rg2, ahn[2], AXN[2]);                              \
      const float na3 = fmaf(rg3, ahn[3], AXN[3]);                              \
      const float ng0 = fmaf(-2.0f,                                             \
          __builtin_amdgcn_rcpf(__builtin_amdgcn_exp2f(na0) + 1.0f), 1.0f);     \
      const float ng1 = fmaf(-2.0f,                                             \
          __builtin_amdgcn_rcpf(__builtin_amdgcn_exp2f(na1) + 1.0f), 1.0f);     \
      const float ng2 = fmaf(-2.0f,                                             \
          __builtin_amdgcn_rcpf(__builtin_amdgcn_exp2f(na2) + 1.0f), 1.0f);     \
      const float ng3 = fmaf(-2.0f,                                             \
          __builtin_amdgcn_rcpf(__builtin_amdgcn_exp2f(na3) + 1.0f), 1.0f);     \
      hprev[0] = fmaf(zg0, hprev[0] - ng0, ng0);                                \
      hprev[1] = fmaf(zg1, hprev[1] - ng1, ng1);                                \
      hprev[2] = fmaf(zg2, hprev[2] - ng2, ng2);                                \
      hprev[3] = fmaf(zg3, hprev[3] - ng3, ng3);                                \
    }                                                                           \
    BXN = mfma16(wih[2][0], xf0, bias_xn);                                      \
    BXN = mfma16(wih[2][1], xf1, BXN);                                          \
    {                                                                           \
      union { bhalf4 v; unsigned u[2]; } hp;                                    \
      hp.u[0] = cvtpk(hprev[0], hprev[1]);                                      \
      hp.u[1] = cvtpk(hprev[2], hprev[3]);                                      \
      *(bhalf4*)((tp & 1) ? hw1 : hw0) = hp.v;                                  \
    }                                                                           \
    if (tp == 4 && more) { /* write staged chunk into other x buffer */         \
      short* xd = xstA + ((c + 1) & 1) * (CHUNK * BC * XROW);                   \
      union { bhalf8 v; unsigned u[4]; } cv;                                    \
      cv.u[0] = cvtpk(xl0.x, xl0.y); cv.u[1] = cvtpk(xl0.z, xl0.w);             \
      cv.u[2] = cvtpk(xl1.x, xl1.y); cv.u[3] = cvtpk(xl1.z, xl1.w);             \
      *(bhalf8*)xd = cv.v;                                                      \
      cv.u[0] = cvtpk(xl2.x, xl2.y); cv.u[1] = cvtpk(xl2.z, xl2.w);             \
      cv.u[2] = cvtpk(xl3.x, xl3.y); cv.u[3] = cvtpk(xl3.z, xl3.w);             \
      *(bhalf8*)(xd + 4 * (BC * XROW)) = cv.v;                                  \
    }                                                                           \
    bar_lgkm();                                                                 \
  }

__global__ __launch_bounds__(NTHR) __attribute__((amdgpu_waves_per_eu(2, 2)))
void gru_fused(
    const float* __restrict__ xin, const float* __restrict__ Wih,
    const float* __restrict__ Whh, const float* __restrict__ bih,
    const float* __restrict__ bhh, const float* __restrict__ Wfc,
    const float* __restrict__ bfc, float* __restrict__ out)
{
  __shared__ short xsh[2][CHUNK][BC * XROW];
  __shared__ short hsh[2][BC * HROW];
  __shared__ float slut[4096];  // sigmoid over xh in [-8,8), step 1/256

  const int tid = threadIdx.x;
  const int lane = tid & 63;
  const int wv = tid >> 6;
  const int q = lane >> 4;
  const int c15 = lane & 15;
  const int b0 = blockIdx.x * BC;

  // build sigmoid LUT (exp2-domain argument)
  for (int i = tid; i < 4096; i += NTHR) {
    const float xh = (float)(i - 2048) * (1.0f / 256.0f);
    slut[i] = __builtin_amdgcn_rcpf(1.0f + __builtin_amdgcn_exp2f(-xh));
  }

  // resident weight fragments, prescaled: r,z by log2e; n by 2*log2e
  bhalf8 whh[3][4];
  bhalf8 wih[3][2];
#pragma unroll
  for (int g = 0; g < 3; ++g) {
    const float sc = (g == 2) ? 2.0f * L2E : L2E;
    const int grow = g * HH + wv * 16 + c15;
#pragma unroll
    for (int kt = 0; kt < 4; ++kt)
      whh[g][kt] = packrow8s(Whh + grow * HH + kt * 32 + q * 8, sc);
#pragma unroll
    for (int kt = 0; kt < 2; ++kt)
      wih[g][kt] = packrow8s(Wih + grow * II + kt * 32 + q * 8, sc);
  }

  f32x4 bias_r, bias_z, bias_hn, bias_xn;
#pragma unroll
  for (int r = 0; r < 4; ++r) {
    const int d = wv * 16 + q * 4 + r;
    bias_r[r]  = (bih[d] + bhh[d]) * L2E;
    bias_z[r]  = (bih[HH + d] + bhh[HH + d]) * L2E;
    bias_xn[r] = bih[2 * HH + d] * (2.0f * L2E);
    bias_hn[r] = bhh[2 * HH + d] * (2.0f * L2E);
  }

  for (int i = tid; i < BC * HROW; i += NTHR) hsh[0][i] = 0;

  const int tpA = tid >> 7, bs = (tid >> 3) & 15, g8 = tid & 7;
  const float* xsrcA = xin + (size_t)(b0 + bs) * (TT * II) + tpA * II + g8 * 8;
  short* xstA = &xsh[0][tpA][bs * XROW + g8 * 8];

  float4 xl0, xl1, xl2, xl3;
  // stage chunk 0
  {
    float4 a0 = *(const float4*)(xsrcA);
    float4 a1 = *(const float4*)(xsrcA + 4);
    float4 a2 = *(const float4*)(xsrcA + 4 * II);
    float4 a3 = *(const float4*)(xsrcA + 4 * II + 4);
    union { bhalf8 v; unsigned u[4]; } cv;
    cv.u[0] = cvtpk(a0.x, a0.y); cv.u[1] = cvtpk(a0.z, a0.w);
    cv.u[2] = cvtpk(a1.x, a1.y); cv.u[3] = cvtpk(a1.z, a1.w);
    *(bhalf8*)xstA = cv.v;
    cv.u[0] = cvtpk(a2.x, a2.y); cv.u[1] = cvtpk(a2.z, a2.w);
    cv.u[2] = cvtpk(a3.x, a3.y); cv.u[3] = cvtpk(a3.z, a3.w);
    *(bhalf8*)(xstA + 4 * (BC * XROW)) = cv.v;
  }
  __syncthreads();

  const short* hrd0 = &hsh[0][c15 * HROW];
  const short* hrd1 = &hsh[1][c15 * HROW];
  short* hw0 = &hsh[1][c15 * HROW + wv * 16 + q * 4];  // write when t even
  short* hw1 = &hsh[0][c15 * HROW + wv * 16 + q * 4];  // write when t odd
  const short* xbase = &xsh[0][0][c15 * XROW];

  f32x4 hprev = {0.f, 0.f, 0.f, 0.f};
  f32x4 aR, aZ, aXN, bR, bZ, bXN;

  // prologue: fill set A for t=0
  {
    bhalf8 xf0 = *(const bhalf8*)(xbase + q * 8);
    bhalf8 xf1 = *(const bhalf8*)(xbase + 32 + q * 8);
    aR  = mfma16(wih[0][0], xf0, bias_r);
    aR  = mfma16(wih[0][1], xf1, aR);
    aZ  = mfma16(wih[1][0], xf0, bias_z);
    aZ  = mfma16(wih[1][1], xf1, aZ);
    aXN = mfma16(wih[2][0], xf0, bias_xn);
    aXN = mfma16(wih[2][1], xf1, aXN);
  }

#pragma unroll 1
  for (int c = 0; c < TT / CHUNK; ++c) {
    const int more = (c + 1 < TT / CHUNK);
    DOSTEP(0, aR, aZ, aXN, bR, bZ, bXN)
    DOSTEP(1, bR, bZ, bXN, aR, aZ, aXN)
    DOSTEP(2, aR, aZ, aXN, bR, bZ, bXN)
    DOSTEP(3, bR, bZ, bXN, aR, aZ, aXN)
    DOSTEP(4, aR, aZ, aXN, bR, bZ, bXN)
    DOSTEP(5, bR, bZ, bXN, aR, aZ, aXN)
    DOSTEP(6, aR, aZ, aXN, bR, bZ, bXN)
    DOSTEP(7, bR, bZ, bXN, aR, aZ, aXN)
  }

  // FC head: h_T is in hsh[0]
  for (int idx = tid; idx < BC * 51; idx += NTHR) {
    const int bb = idx / 51;
    const int o = idx - bb * 51;
    const float* wf = Wfc + o * HH;
    const short* hr = &hsh[0][bb * HROW];
    float s = bfc[o];
#pragma unroll
    for (int d = 0; d < HH; d += 4) {
      const float4 wvv = *(const float4*)(wf + d);
      s += bf2f(hr[d]) * wvv.x + bf2f(hr[d + 1]) * wvv.y
         + bf2f(hr[d + 2]) * wvv.z + bf2f(hr[d + 3]) * wvv.w;
    }
    out[(size_t)(b0 + bb) * 51 + o] = s;
  }
}

extern "C" void kernel_launch(void* const* d_in, const int* in_sizes, int n_in,
                              void* d_out, int out_size, void* d_ws, size_t ws_size,
                              hipStream_t stream) {
  const float* xin = (const float*)d_in[0];
  const float* Wih = (const float*)d_in[1];
  const float* Whh = (const float*)d_in[2];
  const float* bih = (const float*)d_in[3];
  const float* bhh = (const float*)d_in[4];
  const float* Wfc = (const float*)d_in[5];
  const float* bfc = (const float*)d_in[6];
  float* o = (float*)d_out;
  hipLaunchKernelGGL(gru_fused, dim3(BATCH / BC), dim3(NTHR), 0, stream,
                     xin, Wih, Whh, bih, bhh, Wfc, bfc, o);
}

// Round 10
// 613.129 us; speedup vs baseline: 1.0489x; 1.0489x over previous
//
#include <hip/hip_runtime.h>
#include <hip/hip_bf16.h>

#define TT    1024
#define BATCH 512
#define HH    128
#define II    64
#define BC    16
#define NTHR  512
#define CHUNK 8
#define NC    (TT / CHUNK)
#define XROW  72   // shorts per x row: 64 data + 8 pad
#define HROW  136  // shorts per h row: 128 data + 8 pad
#define L2E   1.4426950408889634f

typedef __attribute__((ext_vector_type(8))) short bhalf8;
typedef __attribute__((ext_vector_type(4))) short bhalf4;
typedef __attribute__((ext_vector_type(4))) float f32x4;

static __device__ __forceinline__ unsigned cvtpk(float lo, float hi) {
  unsigned r;
  asm("v_cvt_pk_bf16_f32 %0, %1, %2" : "=v"(r) : "v"(lo), "v"(hi));
  return r;
}
static __device__ __forceinline__ float bf2f(short s) {
  return __builtin_bit_cast(float, ((unsigned)(unsigned short)s) << 16);
}
static __device__ __forceinline__ f32x4 mfma16(bhalf8 a, bhalf8 b, f32x4 c) {
  return __builtin_amdgcn_mfma_f32_16x16x32_bf16(a, b, c, 0, 0, 0);
}
static __device__ __forceinline__ bhalf8 packrow8s(const float* p, float s) {
  union { bhalf8 v; unsigned u[4]; } cv;
  cv.u[0] = cvtpk(p[0] * s, p[1] * s);
  cv.u[1] = cvtpk(p[2] * s, p[3] * s);
  cv.u[2] = cvtpk(p[4] * s, p[5] * s);
  cv.u[3] = cvtpk(p[6] * s, p[7] * s);
  return cv.v;
}
// barrier without vmcnt drain; lgkmcnt(0) orders LDS
static __device__ __forceinline__ void bar_lgkm() {
  asm volatile("s_waitcnt lgkmcnt(0)\n\ts_barrier" ::: "memory");
}

#define SIG1(x) __builtin_amdgcn_rcpf(1.0f + __builtin_amdgcn_exp2f(-(x)))

// R5 structure (measured best: step = 576 MFMA-issue + 747 VALU-issue + 61
// stall, additive per-SIMD). This pass only removes issue cycles: branchless
// last chunk (clamped prefetch source), hoisted per-chunk x pointers.
#define DOSTEP(TP, AR, AZ, AXN, BR, BZ, BXN)                                    \
  {                                                                             \
    constexpr int tp = (TP);                                                    \
    const short* hrow = (tp & 1) ? hrd1 : hrd0;                                 \
    bhalf8 hf0 = *(const bhalf8*)(hrow + q * 8);                                \
    bhalf8 hf1 = *(const bhalf8*)(hrow + 32 + q * 8);                           \
    bhalf8 hf2 = *(const bhalf8*)(hrow + 64 + q * 8);                           \
    bhalf8 hf3 = *(const bhalf8*)(hrow + 96 + q * 8);                           \
    /* x frags for t+1: tp<7 -> current chunk buffer, tp==7 -> next buffer */   \
    const short* xrow = ((tp == 7) ? xb_nxt : xb_cur) + ((tp + 1) & 7) * (BC * XROW); \
    bhalf8 xf0 = *(const bhalf8*)(xrow + q * 8);                                \
    bhalf8 xf1 = *(const bhalf8*)(xrow + 32 + q * 8);                           \
    if constexpr (tp == 0) { /* issue next-chunk loads (clamped src, no branch)*/\
      xl0 = *(const float4*)(xsrcN);                                            \
      xl1 = *(const float4*)(xsrcN + 4);                                        \
      xl2 = *(const float4*)(xsrcN + 4 * II);                                   \
      xl3 = *(const float4*)(xsrcN + 4 * II + 4);                               \
    }                                                                           \
    /* h-side MFMAs, grouped by acc chain (ar first -> rg starts early) */      \
    AR  = mfma16(whh[0][0], hf0, AR);  AR  = mfma16(whh[0][1], hf1, AR);        \
    AR  = mfma16(whh[0][2], hf2, AR);  AR  = mfma16(whh[0][3], hf3, AR);        \
    AZ  = mfma16(whh[1][0], hf0, AZ);  AZ  = mfma16(whh[1][1], hf1, AZ);        \
    AZ  = mfma16(whh[1][2], hf2, AZ);  AZ  = mfma16(whh[1][3], hf3, AZ);        \
    f32x4 ahn = mfma16(whh[2][0], hf0, bias_hn);                                \
    ahn = mfma16(whh[2][1], hf1, ahn);                                          \
    ahn = mfma16(whh[2][2], hf2, ahn);                                          \
    ahn = mfma16(whh[2][3], hf3, ahn);                                          \
    const float rg0 = SIG1(AR[0]), rg1 = SIG1(AR[1]);                           \
    const float rg2 = SIG1(AR[2]), rg3 = SIG1(AR[3]);                           \
    BR = mfma16(wih[0][0], xf0, bias_r);                                        \
    BR = mfma16(wih[0][1], xf1, BR);                                            \
    const float zg0 = SIG1(AZ[0]), zg1 = SIG1(AZ[1]);                           \
    const float zg2 = SIG1(AZ[2]), zg3 = SIG1(AZ[3]);                           \
    BZ = mfma16(wih[1][0], xf0, bias_z);                                        \
    BZ = mfma16(wih[1][1], xf1, BZ);                                            \
    {                                                                           \
      const float na0 = fmaf(rg0, ahn[0], AXN[0]);                              \
      const float na1 = fmaf(rg1, ahn[1], AXN[1]);                              \
      const float na2 = fmaf(rg2, ahn[2], AXN[2]);                              \
      const float na3 = fmaf(rg3, ahn[3], AXN[3]);                              \
      const float ng0 = fmaf(-2.0f,                                             \
          __builtin_amdgcn_rcpf(__builtin_amdgcn_exp2f(na0) + 1.0f), 1.0f);     \
      const float ng1 = fmaf(-2.0f,                                             \
          __builtin_amdgcn_rcpf(__builtin_amdgcn_exp2f(na1) + 1.0f), 1.0f);     \
      const float ng2 = fmaf(-2.0f,                                             \
          __builtin_amdgcn_rcpf(__builtin_amdgcn_exp2f(na2) + 1.0f), 1.0f);     \
      const float ng3 = fmaf(-2.0f,                                             \
          __builtin_amdgcn_rcpf(__builtin_amdgcn_exp2f(na3) + 1.0f), 1.0f);     \
      hprev[0] = fmaf(zg0, hprev[0] - ng0, ng0);                                \
      hprev[1] = fmaf(zg1, hprev[1] - ng1, ng1);                                \
      hprev[2] = fmaf(zg2, hprev[2] - ng2, ng2);                                \
      hprev[3] = fmaf(zg3, hprev[3] - ng3, ng3);                                \
    }                                                                           \
    BXN = mfma16(wih[2][0], xf0, bias_xn);                                      \
    BXN = mfma16(wih[2][1], xf1, BXN);                                          \
    {                                                                           \
      union { bhalf4 v; unsigned u[2]; } hp;                                    \
      hp.u[0] = cvtpk(hprev[0], hprev[1]);                                      \
      hp.u[1] = cvtpk(hprev[2], hprev[3]);                                      \
      *(bhalf4*)((tp & 1) ? hw1 : hw0) = hp.v;                                  \
    }                                                                           \
    if constexpr (tp == 4) { /* write staged chunk into other x buffer       */ \
      /* last chunk: re-writes dead chunk data into the dead buffer - safe  */  \
      short* xd = xstA + ((c + 1) & 1) * (CHUNK * BC * XROW);                   \
      union { bhalf8 v; unsigned u[4]; } cv;                                    \
      cv.u[0] = cvtpk(xl0.x, xl0.y); cv.u[1] = cvtpk(xl0.z, xl0.w);             \
      cv.u[2] = cvtpk(xl1.x, xl1.y); cv.u[3] = cvtpk(xl1.z, xl1.w);             \
      *(bhalf8*)xd = cv.v;                                                      \
      cv.u[0] = cvtpk(xl2.x, xl2.y); cv.u[1] = cvtpk(xl2.z, xl2.w);             \
      cv.u[2] = cvtpk(xl3.x, xl3.y); cv.u[3] = cvtpk(xl3.z, xl3.w);             \
      *(bhalf8*)(xd + 4 * (BC * XROW)) = cv.v;                                  \
    }                                                                           \
    bar_lgkm();                                                                 \
  }

__global__ __launch_bounds__(NTHR) __attribute__((amdgpu_waves_per_eu(2, 2)))
void gru_fused(
    const float* __restrict__ xin, const float* __restrict__ Wih,
    const float* __restrict__ Whh, const float* __restrict__ bih,
    const float* __restrict__ bhh, const float* __restrict__ Wfc,
    const float* __restrict__ bfc, float* __restrict__ out)
{
  __shared__ short xsh[2][CHUNK][BC * XROW];
  __shared__ short hsh[2][BC * HROW];

  const int tid = threadIdx.x;
  const int lane = tid & 63;
  const int wv = tid >> 6;
  const int q = lane >> 4;
  const int c15 = lane & 15;
  const int b0 = blockIdx.x * BC;

  // resident weight fragments, prescaled: r,z by log2e; n by 2*log2e
  bhalf8 whh[3][4];
  bhalf8 wih[3][2];
#pragma unroll
  for (int g = 0; g < 3; ++g) {
    const float sc = (g == 2) ? 2.0f * L2E : L2E;
    const int grow = g * HH + wv * 16 + c15;
#pragma unroll
    for (int kt = 0; kt < 4; ++kt)
      whh[g][kt] = packrow8s(Whh + grow * HH + kt * 32 + q * 8, sc);
#pragma unroll
    for (int kt = 0; kt < 2; ++kt)
      wih[g][kt] = packrow8s(Wih + grow * II + kt * 32 + q * 8, sc);
  }

  f32x4 bias_r, bias_z, bias_hn, bias_xn;
#pragma unroll
  for (int r = 0; r < 4; ++r) {
    const int d = wv * 16 + q * 4 + r;
    bias_r[r]  = (bih[d] + bhh[d]) * L2E;
    bias_z[r]  = (bih[HH + d] + bhh[HH + d]) * L2E;
    bias_xn[r] = bih[2 * HH + d] * (2.0f * L2E);
    bias_hn[r] = bhh[2 * HH + d] * (2.0f * L2E);
  }

  for (int i = tid; i < BC * HROW; i += NTHR) hsh[0][i] = 0;

  const int tpA = tid >> 7, bs = (tid >> 3) & 15, g8 = tid & 7;
  const float* xsrcA = xin + (size_t)(b0 + bs) * (TT * II) + tpA * II + g8 * 8;
  short* xstA = &xsh[0][tpA][bs * XROW + g8 * 8];

  float4 xl0, xl1, xl2, xl3;
  // stage chunk 0
  {
    float4 a0 = *(const float4*)(xsrcA);
    float4 a1 = *(const float4*)(xsrcA + 4);
    float4 a2 = *(const float4*)(xsrcA + 4 * II);
    float4 a3 = *(const float4*)(xsrcA + 4 * II + 4);
    union { bhalf8 v; unsigned u[4]; } cv;
    cv.u[0] = cvtpk(a0.x, a0.y); cv.u[1] = cvtpk(a0.z, a0.w);
    cv.u[2] = cvtpk(a1.x, a1.y); cv.u[3] = cvtpk(a1.z, a1.w);
    *(bhalf8*)xstA = cv.v;
    cv.u[0] = cvtpk(a2.x, a2.y); cv.u[1] = cvtpk(a2.z, a2.w);
    cv.u[2] = cvtpk(a3.x, a3.y); cv.u[3] = cvtpk(a3.z, a3.w);
    *(bhalf8*)(xstA + 4 * (BC * XROW)) = cv.v;
  }
  __syncthreads();

  const short* hrd0 = &hsh[0][c15 * HROW];
  const short* hrd1 = &hsh[1][c15 * HROW];
  short* hw0 = &hsh[1][c15 * HROW + wv * 16 + q * 4];  // write when t even
  short* hw1 = &hsh[0][c15 * HROW + wv * 16 + q * 4];  // write when t odd
  const short* xbase = &xsh[0][0][c15 * XROW];

  f32x4 hprev = {0.f, 0.f, 0.f, 0.f};
  f32x4 aR, aZ, aXN, bR, bZ, bXN;

  // prologue: fill set A for t=0
  {
    bhalf8 xf0 = *(const bhalf8*)(xbase + q * 8);
    bhalf8 xf1 = *(const bhalf8*)(xbase + 32 + q * 8);
    aR  = mfma16(wih[0][0], xf0, bias_r);
    aR  = mfma16(wih[0][1], xf1, aR);
    aZ  = mfma16(wih[1][0], xf0, bias_z);
    aZ  = mfma16(wih[1][1], xf1, aZ);
    aXN = mfma16(wih[2][0], xf0, bias_xn);
    aXN = mfma16(wih[2][1], xf1, aXN);
  }

#pragma unroll 1
  for (int c = 0; c < NC; ++c) {
    const int cn = (c + 1 < NC) ? c + 1 : c;             // clamped (branchless)
    const float* xsrcN = xsrcA + (size_t)cn * (CHUNK * II);  // prefetch src
    const short* xb_cur = xbase + (c & 1) * (CHUNK * BC * XROW);
    const short* xb_nxt = xbase + ((c + 1) & 1) * (CHUNK * BC * XROW);
    DOSTEP(0, aR, aZ, aXN, bR, bZ, bXN)
    DOSTEP(1, bR, bZ, bXN, aR, aZ, aXN)
    DOSTEP(2, aR, aZ, aXN, bR, bZ, bXN)
    DOSTEP(3, bR, bZ, bXN, aR, aZ, aXN)
    DOSTEP(4, aR, aZ, aXN, bR, bZ, bXN)
    DOSTEP(5, bR, bZ, bXN, aR, aZ, aXN)
    DOSTEP(6, aR, aZ, aXN, bR, bZ, bXN)
    DOSTEP(7, bR, bZ, bXN, aR, aZ, aXN)
  }

  // FC head: h_T is in hsh[0]
  for (int idx = tid; idx < BC * 51; idx += NTHR) {
    const int bb = idx / 51;
    const int o = idx - bb * 51;
    const float* wf = Wfc + o * HH;
    const short* hr = &hsh[0][bb * HROW];
    float s = bfc[o];
#pragma unroll
    for (int d = 0; d < HH; d += 4) {
      const float4 wvv = *(const float4*)(wf + d);
      s += bf2f(hr[d]) * wvv.x + bf2f(hr[d + 1]) * wvv.y
         + bf2f(hr[d + 2]) * wvv.z + bf2f(hr[d + 3]) * wvv.w;
    }
    out[(size_t)(b0 + bb) * 51 + o] = s;
  }
}

extern "C" void kernel_launch(void* const* d_in, const int* in_sizes, int n_in,
                              void* d_out, int out_size, void* d_ws, size_t ws_size,
                              hipStream_t stream) {
  const float* xin = (const float*)d_in[0];
  const float* Wih = (const float*)d_in[1];
  const float* Whh = (const float*)d_in[2];
  const float* bih = (const float*)d_in[3];
  const float* bhh = (const float*)d_in[4];
  const float* Wfc = (const float*)d_in[5];
  const float* bfc = (const float*)d_in[6];
  float* o = (float*)d_out;
  hipLaunchKernelGGL(gru_fused, dim3(BATCH / BC), dim3(NTHR), 0, stream,
                     xin, Wih, Whh, bih, bhh, Wfc, bfc, o);
}

// Round 11
// 584.094 us; speedup vs baseline: 1.1011x; 1.0497x over previous
//
#include <hip/hip_runtime.h>
#include <hip/hip_bf16.h>

#define TT    1024
#define BATCH 512
#define HH    128
#define II    64
#define BC    16
#define NTHR  512
#define CHUNK 8
#define XROW  72   // shorts per x row: 64 data + 8 pad
#define HROW  136  // shorts per h row: 128 data + 8 pad
#define L2E   1.4426950408889634f

typedef __attribute__((ext_vector_type(8))) short bhalf8;
typedef __attribute__((ext_vector_type(4))) short bhalf4;
typedef __attribute__((ext_vector_type(4))) float f32x4;

static __device__ __forceinline__ unsigned cvtpk(float lo, float hi) {
  unsigned r;
  asm("v_cvt_pk_bf16_f32 %0, %1, %2" : "=v"(r) : "v"(lo), "v"(hi));
  return r;
}
static __device__ __forceinline__ float bf2f(short s) {
  return __builtin_bit_cast(float, ((unsigned)(unsigned short)s) << 16);
}
static __device__ __forceinline__ f32x4 mfma16(bhalf8 a, bhalf8 b, f32x4 c) {
  return __builtin_amdgcn_mfma_f32_16x16x32_bf16(a, b, c, 0, 0, 0);
}
static __device__ __forceinline__ bhalf8 packrow8s(const float* p, float s) {
  union { bhalf8 v; unsigned u[4]; } cv;
  cv.u[0] = cvtpk(p[0] * s, p[1] * s);
  cv.u[1] = cvtpk(p[2] * s, p[3] * s);
  cv.u[2] = cvtpk(p[4] * s, p[5] * s);
  cv.u[3] = cvtpk(p[6] * s, p[7] * s);
  return cv.v;
}
// barrier without vmcnt drain; lgkmcnt(0) orders LDS
static __device__ __forceinline__ void bar_lgkm() {
  asm volatile("s_waitcnt lgkmcnt(0)\n\ts_barrier" ::: "memory");
}

#define SIG1(x) __builtin_amdgcn_rcpf(1.0f + __builtin_amdgcn_exp2f(-(x)))

// Measured-best step structure (R5, 585us). Per-SIMD additive-issue model:
// step = MFMA-issue (570cy) + VALU-issue (747cy, 384 trans) + ~61 stall.
// Every structural deviation tried (R6-R10) regressed; do not perturb.
#define DOSTEP(TP, AR, AZ, AXN, BR, BZ, BXN)                                    \
  {                                                                             \
    constexpr int tp = (TP);                                                    \
    const short* hrow = (tp & 1) ? hrd1 : hrd0;                                 \
    bhalf8 hf0 = *(const bhalf8*)(hrow + q * 8);                                \
    bhalf8 hf1 = *(const bhalf8*)(hrow + 32 + q * 8);                           \
    bhalf8 hf2 = *(const bhalf8*)(hrow + 64 + q * 8);                           \
    bhalf8 hf3 = *(const bhalf8*)(hrow + 96 + q * 8);                           \
    const int nb2 = (tp == 7) ? ((c + 1) & 1) : (c & 1);                        \
    const short* xrow = xbase + nb2 * (CHUNK * BC * XROW)                       \
                              + ((tp + 1) & 7) * (BC * XROW);                   \
    bhalf8 xf0 = *(const bhalf8*)(xrow + q * 8);                                \
    bhalf8 xf1 = *(const bhalf8*)(xrow + 32 + q * 8);                           \
    if (tp == 0 && more) { /* issue next-chunk global loads */                  \
      const float* sA = xsrcA + (size_t)(c + 1) * (CHUNK * II);                 \
      xl0 = *(const float4*)(sA);                                               \
      xl1 = *(const float4*)(sA + 4);                                           \
      xl2 = *(const float4*)(sA + 4 * II);                                      \
      xl3 = *(const float4*)(sA + 4 * II + 4);                                  \
    }                                                                           \
    /* h-side MFMAs, grouped by acc chain (ar first -> rg can start early) */   \
    AR  = mfma16(whh[0][0], hf0, AR);  AR  = mfma16(whh[0][1], hf1, AR);        \
    AR  = mfma16(whh[0][2], hf2, AR);  AR  = mfma16(whh[0][3], hf3, AR);        \
    AZ  = mfma16(whh[1][0], hf0, AZ);  AZ  = mfma16(whh[1][1], hf1, AZ);        \
    AZ  = mfma16(whh[1][2], hf2, AZ);  AZ  = mfma16(whh[1][3], hf3, AZ);        \
    f32x4 ahn = mfma16(whh[2][0], hf0, bias_hn);                                \
    ahn = mfma16(whh[2][1], hf1, ahn);                                          \
    ahn = mfma16(whh[2][2], hf2, ahn);                                          \
    ahn = mfma16(whh[2][3], hf3, ahn);                                          \
    const float rg0 = SIG1(AR[0]), rg1 = SIG1(AR[1]);                           \
    const float rg2 = SIG1(AR[2]), rg3 = SIG1(AR[3]);                           \
    BR = mfma16(wih[0][0], xf0, bias_r);                                        \
    BR = mfma16(wih[0][1], xf1, BR);                                            \
    const float zg0 = SIG1(AZ[0]), zg1 = SIG1(AZ[1]);                           \
    const float zg2 = SIG1(AZ[2]), zg3 = SIG1(AZ[3]);                           \
    BZ = mfma16(wih[1][0], xf0, bias_z);                                        \
    BZ = mfma16(wih[1][1], xf1, BZ);                                            \
    {                                                                           \
      const float na0 = fmaf(rg0, ahn[0], AXN[0]);                              \
      const float na1 = fmaf(rg1, ahn[1], AXN[1]);                              \
      const float na2 = fmaf(rg2, ahn[2], AXN[2]);                              \
      const float na3 = fmaf(rg3, ahn[3], AXN[3]);                              \
      const float ng0 = fmaf(-2.0f,                                             \
          __builtin_amdgcn_rcpf(__builtin_amdgcn_exp2f(na0) + 1.0f), 1.0f);     \
      const float ng1 = fmaf(-2.0f,                                             \
          __builtin_amdgcn_rcpf(__builtin_amdgcn_exp2f(na1) + 1.0f), 1.0f);     \
      const float ng2 = fmaf(-2.0f,                                             \
          __builtin_amdgcn_rcpf(__builtin_amdgcn_exp2f(na2) + 1.0f), 1.0f);     \
      const float ng3 = fmaf(-2.0f,                                             \
          __builtin_amdgcn_rcpf(__builtin_amdgcn_exp2f(na3) + 1.0f), 1.0f);     \
      hprev[0] = fmaf(zg0, hprev[0] - ng0, ng0);                                \
      hprev[1] = fmaf(zg1, hprev[1] - ng1, ng1);                                \
      hprev[2] = fmaf(zg2, hprev[2] - ng2, ng2);                                \
      hprev[3] = fmaf(zg3, hprev[3] - ng3, ng3);                                \
    }                                                                           \
    BXN = mfma16(wih[2][0], xf0, bias_xn);                                      \
    BXN = mfma16(wih[2][1], xf1, BXN);                                          \
    {                                                                           \
      union { bhalf4 v; unsigned u[2]; } hp;                                    \
      hp.u[0] = cvtpk(hprev[0], hprev[1]);                                      \
      hp.u[1] = cvtpk(hprev[2], hprev[3]);                                      \
      *(bhalf4*)((tp & 1) ? hw1 : hw0) = hp.v;                                  \
    }                                                                           \
    if (tp == 4 && more) { /* write staged chunk into other x buffer */         \
      short* xd = xstA + ((c + 1) & 1) * (CHUNK * BC * XROW);                   \
      union { bhalf8 v; unsigned u[4]; } cv;                                    \
      cv.u[0] = cvtpk(xl0.x, xl0.y); cv.u[1] = cvtpk(xl0.z, xl0.w);             \
      cv.u[2] = cvtpk(xl1.x, xl1.y); cv.u[3] = cvtpk(xl1.z, xl1.w);             \
      *(bhalf8*)xd = cv.v;                                                      \
      cv.u[0] = cvtpk(xl2.x, xl2.y); cv.u[1] = cvtpk(xl2.z, xl2.w);             \
      cv.u[2] = cvtpk(xl3.x, xl3.y); cv.u[3] = cvtpk(xl3.z, xl3.w);             \
      *(bhalf8*)(xd + 4 * (BC * XROW)) = cv.v;                                  \
    }                                                                           \
    bar_lgkm();                                                                 \
  }

__global__ __launch_bounds__(NTHR) __attribute__((amdgpu_waves_per_eu(2, 2)))
void gru_fused(
    const float* __restrict__ xin, const float* __restrict__ Wih,
    const float* __restrict__ Whh, const float* __restrict__ bih,
    const float* __restrict__ bhh, const float* __restrict__ Wfc,
    const float* __restrict__ bfc, float* __restrict__ out)
{
  __shared__ short xsh[2][CHUNK][BC * XROW];
  __shared__ short hsh[2][BC * HROW];

  const int tid = threadIdx.x;
  const int lane = tid & 63;
  const int wv = tid >> 6;
  const int q = lane >> 4;
  const int c15 = lane & 15;
  const int b0 = blockIdx.x * BC;

  // resident weight fragments, prescaled: r,z by log2e; n by 2*log2e
  bhalf8 whh[3][4];
  bhalf8 wih[3][2];
#pragma unroll
  for (int g = 0; g < 3; ++g) {
    const float sc = (g == 2) ? 2.0f * L2E : L2E;
    const int grow = g * HH + wv * 16 + c15;
#pragma unroll
    for (int kt = 0; kt < 4; ++kt)
      whh[g][kt] = packrow8s(Whh + grow * HH + kt * 32 + q * 8, sc);
#pragma unroll
    for (int kt = 0; kt < 2; ++kt)
      wih[g][kt] = packrow8s(Wih + grow * II + kt * 32 + q * 8, sc);
  }

  f32x4 bias_r, bias_z, bias_hn, bias_xn;
#pragma unroll
  for (int r = 0; r < 4; ++r) {
    const int d = wv * 16 + q * 4 + r;
    bias_r[r]  = (bih[d] + bhh[d]) * L2E;
    bias_z[r]  = (bih[HH + d] + bhh[HH + d]) * L2E;
    bias_xn[r] = bih[2 * HH + d] * (2.0f * L2E);
    bias_hn[r] = bhh[2 * HH + d] * (2.0f * L2E);
  }

  for (int i = tid; i < BC * HROW; i += NTHR) hsh[0][i] = 0;

  const int tpA = tid >> 7, bs = (tid >> 3) & 15, g8 = tid & 7;
  const float* xsrcA = xin + (size_t)(b0 + bs) * (TT * II) + tpA * II + g8 * 8;
  short* xstA = &xsh[0][tpA][bs * XROW + g8 * 8];

  float4 xl0, xl1, xl2, xl3;
  // stage chunk 0
  {
    float4 a0 = *(const float4*)(xsrcA);
    float4 a1 = *(const float4*)(xsrcA + 4);
    float4 a2 = *(const float4*)(xsrcA + 4 * II);
    float4 a3 = *(const float4*)(xsrcA + 4 * II + 4);
    union { bhalf8 v; unsigned u[4]; } cv;
    cv.u[0] = cvtpk(a0.x, a0.y); cv.u[1] = cvtpk(a0.z, a0.w);
    cv.u[2] = cvtpk(a1.x, a1.y); cv.u[3] = cvtpk(a1.z, a1.w);
    *(bhalf8*)xstA = cv.v;
    cv.u[0] = cvtpk(a2.x, a2.y); cv.u[1] = cvtpk(a2.z, a2.w);
    cv.u[2] = cvtpk(a3.x, a3.y); cv.u[3] = cvtpk(a3.z, a3.w);
    *(bhalf8*)(xstA + 4 * (BC * XROW)) = cv.v;
  }
  __syncthreads();

  const short* hrd0 = &hsh[0][c15 * HROW];
  const short* hrd1 = &hsh[1][c15 * HROW];
  short* hw0 = &hsh[1][c15 * HROW + wv * 16 + q * 4];  // write when t even
  short* hw1 = &hsh[0][c15 * HROW + wv * 16 + q * 4];  // write when t odd
  const short* xbase = &xsh[0][0][c15 * XROW];

  f32x4 hprev = {0.f, 0.f, 0.f, 0.f};
  f32x4 aR, aZ, aXN, bR, bZ, bXN;

  // prologue: fill set A for t=0
  {
    bhalf8 xf0 = *(const bhalf8*)(xbase + q * 8);
    bhalf8 xf1 = *(const bhalf8*)(xbase + 32 + q * 8);
    aR  = mfma16(wih[0][0], xf0, bias_r);
    aR  = mfma16(wih[0][1], xf1, aR);
    aZ  = mfma16(wih[1][0], xf0, bias_z);
    aZ  = mfma16(wih[1][1], xf1, aZ);
    aXN = mfma16(wih[2][0], xf0, bias_xn);
    aXN = mfma16(wih[2][1], xf1, aXN);
  }

#pragma unroll 1
  for (int c = 0; c < TT / CHUNK; ++c) {
    const int more = (c + 1 < TT / CHUNK);
    DOSTEP(0, aR, aZ, aXN, bR, bZ, bXN)
    DOSTEP(1, bR, bZ, bXN, aR, aZ, aXN)
    DOSTEP(2, aR, aZ, aXN, bR, bZ, bXN)
    DOSTEP(3, bR, bZ, bXN, aR, aZ, aXN)
    DOSTEP(4, aR, aZ, aXN, bR, bZ, bXN)
    DOSTEP(5, bR, bZ, bXN, aR, aZ, aXN)
    DOSTEP(6, aR, aZ, aXN, bR, bZ, bXN)
    DOSTEP(7, bR, bZ, bXN, aR, aZ, aXN)
  }

  // FC head: h_T is in hsh[0]
  for (int idx = tid; idx < BC * 51; idx += NTHR) {
    const int bb = idx / 51;
    const int o = idx - bb * 51;
    const float* wf = Wfc + o * HH;
    const short* hr = &hsh[0][bb * HROW];
    float s = bfc[o];
#pragma unroll
    for (int d = 0; d < HH; d += 4) {
      const float4 wvv = *(const float4*)(wf + d);
      s += bf2f(hr[d]) * wvv.x + bf2f(hr[d + 1]) * wvv.y
         + bf2f(hr[d + 2]) * wvv.z + bf2f(hr[d + 3]) * wvv.w;
    }
    out[(size_t)(b0 + bb) * 51 + o] = s;
  }
}

extern "C" void kernel_launch(void* const* d_in, const int* in_sizes, int n_in,
                              void* d_out, int out_size, void* d_ws, size_t ws_size,
                              hipStream_t stream) {
  const float* xin = (const float*)d_in[0];
  const float* Wih = (const float*)d_in[1];
  const float* Whh = (const float*)d_in[2];
  const float* bih = (const float*)d_in[3];
  const float* bhh = (const float*)d_in[4];
  const float* Wfc = (const float*)d_in[5];
  const float* bfc = (const float*)d_in[6];
  float* o = (float*)d_out;
  hipLaunchKernelGGL(gru_fused, dim3(BATCH / BC), dim3(NTHR), 0, stream,
                     xin, Wih, Whh, bih, bhh, Wfc, bfc, o);
}